// Round 9
// baseline (231.086 us; speedup 1.0000x reference)
//
#include <hip/hip_runtime.h>
#include <hip/hip_bf16.h>

#define N_NODES 100000
#define N_EDGES 1000000
#define EMB 64
#define HID 64
#define SCAN_B 256
#define N_BLOCKS_SCAN ((N_NODES + SCAN_B - 1) / SCAN_B)   // 391

// superrange partitioning (hist/coff granularity)
#define RANGES 4
#define RSIZE  25000          // bins per superrange
#define RWORDS 12500          // u32 words (2 x u16 per word)
#define CHUNKS 32
#define CHUNK_EDGES (N_EDGES / CHUNKS)   // 31250
// fill granularity: 8 half-ranges of 12500 bins
#define HRSIZE  12500
#define HRWORDS 6250

// ---------------- workspace layout (bytes) ---------------- (same as R8, ~44 MB)
// ghist_s   [0         .. 6,400,000)   u32[128*12500]
// ghist_r   [6,400,000 ..12,800,000)   u32[128*12500]
// coff      [12,800,000..25,600,000)   int[128*25000]
// cnt_r     [25,600,000..26,000,000)   int[N]
// row_start [26,000,000..26,400,016)   int[N+1]
// blockSums [26,400,016..26,401,580)   int[391]
// blockOffs [26,401,600..26,403,164)   int[391]
// rs        [26,403,200..26,803,200)   float[N]
// col       [26,803,200..30,803,200)   int[E]
// h16       [30,803,200..43,603,200)   ushort[N*64]  bf16
// z         [43,603,200..44,003,200)   float[N]
// NO memset: every buffer densely overwritten before first read.

__device__ __forceinline__ unsigned f32_to_bf16(float v) {
    unsigned u = __float_as_uint(v);
    return (u + 0x7fffu + ((u >> 16) & 1u)) >> 16;     // RNE
}
__device__ __forceinline__ float bf16_to_f32(unsigned b) {
    return __uint_as_float(b << 16);
}

// Histogram both index arrays into per-(arr,superrange,chunk) private copies.
__global__ void k_hist(const int* __restrict__ senders,
                       const int* __restrict__ receivers,
                       unsigned* __restrict__ ghist_s,
                       unsigned* __restrict__ ghist_r) {
    __shared__ unsigned lds[RWORDS];   // 50 KB
    int blk = blockIdx.x;              // [0, 256)
    int arr = blk >> 7;                // 0 = senders, 1 = receivers
    int rem = blk & 127;
    int r   = rem >> 5;                // superrange 0..3
    int c   = rem & 31;                // chunk 0..31
    const int* __restrict__ src = arr ? receivers : senders;
    unsigned* __restrict__ gh   = arr ? ghist_r : ghist_s;
    int t = threadIdx.x;

    for (int w = t; w < RWORDS; w += 1024) lds[w] = 0u;
    __syncthreads();

    int base = r * RSIZE;
    int beg  = c * CHUNK_EDGES;
    int end  = beg + CHUNK_EDGES;
    for (int i = beg + t; i < end; i += 1024) {
        unsigned idx = (unsigned)(src[i] - base);
        if (idx < (unsigned)RSIZE) {
            atomicAdd(&lds[idx >> 1], 1u << ((idx & 1) * 16));
        }
    }
    __syncthreads();

    unsigned* __restrict__ dst = gh + (size_t)rem * RWORDS;
    for (int w = t; w < RWORDS; w += 1024) dst[w] = lds[w];
}

// Merged reduce + scanA: per node, sum chunk copies -> cnt_r (recv) and
// rs (send); block-level inclusive scan of cnt -> blockSums.
__global__ void k_scanA2(const unsigned* __restrict__ ghist_s,
                         const unsigned* __restrict__ ghist_r,
                         int* __restrict__ cnt_r, float* __restrict__ rs,
                         int* __restrict__ blockSums) {
    __shared__ int s[SCAN_B];
    int t = threadIdx.x;
    int idx = blockIdx.x * SCAN_B + t;
    int v = 0;
    if (idx < N_NODES) {
        int r = idx / RSIZE;
        int bin = idx - r * RSIZE;
        int w = bin >> 1, sh = (bin & 1) * 16;
        const unsigned* __restrict__ gr = ghist_r + (size_t)(r * CHUNKS) * RWORDS + w;
        const unsigned* __restrict__ gs = ghist_s + (size_t)(r * CHUNKS) * RWORDS + w;
        unsigned sr_ = 0, ss_ = 0;
#pragma unroll
        for (int c = 0; c < CHUNKS; ++c) {
            sr_ += (gr[(size_t)c * RWORDS] >> sh) & 0xffffu;
            ss_ += (gs[(size_t)c * RWORDS] >> sh) & 0xffffu;
        }
        v = (int)sr_;
        cnt_r[idx] = v;
        rs[idx] = rsqrtf(fmaxf((float)ss_, 1.0f));
    }
    s[t] = v;
    __syncthreads();
    for (int off = 1; off < SCAN_B; off <<= 1) {
        int x = (t >= off) ? s[t - off] : 0;
        __syncthreads();
        s[t] += x;
        __syncthreads();
    }
    if (t == SCAN_B - 1) blockSums[blockIdx.x] = s[t];
}

__global__ void k_scanB(const int* __restrict__ blockSums, int* __restrict__ blockOffs) {
    __shared__ int s[512];
    int t = threadIdx.x;   // 512 threads, 1 block
    int v = (t < N_BLOCKS_SCAN) ? blockSums[t] : 0;
    s[t] = v;
    __syncthreads();
    for (int off = 1; off < 512; off <<= 1) {
        int x = (t >= off) ? s[t - off] : 0;
        __syncthreads();
        s[t] += x;
        __syncthreads();
    }
    if (t < N_BLOCKS_SCAN) blockOffs[t] = s[t] - v;   // exclusive
}

// Merged scanC + scan_chunks: row_start[] plus per-(superrange,chunk,bin)
// absolute base offsets coff[].
__global__ void k_scanCD(const int* __restrict__ cnt_r,
                         const int* __restrict__ blockOffs,
                         const unsigned* __restrict__ ghist_r,
                         int* __restrict__ row_start,
                         int* __restrict__ coff) {
    __shared__ int s[SCAN_B];
    int t = threadIdx.x;
    int idx = blockIdx.x * SCAN_B + t;
    int v = (idx < N_NODES) ? cnt_r[idx] : 0;
    s[t] = v;
    __syncthreads();
    for (int off = 1; off < SCAN_B; off <<= 1) {
        int x = (t >= off) ? s[t - off] : 0;
        __syncthreads();
        s[t] += x;
        __syncthreads();
    }
    if (idx < N_NODES) {
        int run = blockOffs[blockIdx.x] + s[t] - v;   // exclusive prefix
        row_start[idx] = run;
        int r = idx / RSIZE;
        int bin = idx - r * RSIZE;
        int w = bin >> 1, sh = (bin & 1) * 16;
        const unsigned* __restrict__ gr = ghist_r + (size_t)(r * CHUNKS) * RWORDS + w;
        int* __restrict__ co = coff + (size_t)(r * CHUNKS) * RSIZE + bin;
#pragma unroll
        for (int c = 0; c < CHUNKS; ++c) {
            co[(size_t)c * RSIZE] = run;
            run += (int)((gr[(size_t)c * RWORDS] >> sh) & 0xffffu);
        }
    }
    if (blockIdx.x == 0 && t == 0) row_start[N_NODES] = N_EDGES;
}

// Phase 1 (256 blocks = 8 half-ranges x 32 chunks): atomic-free CSR fill via
// LDS rank recompute + plain stores. Phase 2: grid-stride wave-per-node
// h16[n] = bf16((emb[n]*rs[n]) @ W1).
__global__ void k_fill2h(const int* __restrict__ senders,
                         const int* __restrict__ receivers,
                         const int* __restrict__ coff,
                         int* __restrict__ col,
                         const float* __restrict__ emb,
                         const float* __restrict__ rs,
                         const float* __restrict__ W1,
                         unsigned short* __restrict__ h16) {
    __shared__ unsigned lds[HRWORDS];   // 25 KB
    int r8 = blockIdx.x >> 5;           // half-range 0..7
    int c  = blockIdx.x & 31;           // chunk 0..31
    int sr = r8 >> 1;
    int hs = r8 & 1;
    int t  = threadIdx.x;

    for (int w = t; w < HRWORDS; w += 1024) lds[w] = 0u;
    __syncthreads();

    int base = r8 * HRSIZE;
    int beg  = c * CHUNK_EDGES;
    int end  = beg + CHUNK_EDGES;
    const int* __restrict__ co =
        coff + (size_t)(sr * CHUNKS + c) * RSIZE + hs * HRSIZE;
    for (int i = beg + t; i < end; i += 1024) {
        unsigned idx = (unsigned)(receivers[i] - base);
        if (idx < (unsigned)HRSIZE) {
            int sh = (idx & 1) * 16;
            unsigned old = atomicAdd(&lds[idx >> 1], 1u << sh);
            int rank = (int)((old >> sh) & 0xffffu);
            col[co[idx] + rank] = senders[i];
        }
    }

    // ---- phase 2: h compute (independent of phase 1; no syncthreads needed)
    int lane = t & 63;
    int wib  = t >> 6;                      // 0..15
    int gw   = blockIdx.x * 16 + wib;       // 4096 waves
    const int nw = 256 * 16;

    float w1c[64];
#pragma unroll
    for (int k = 0; k < 64; ++k) w1c[k] = W1[k * 64 + lane];

    for (int n = gw; n < N_NODES; n += nw) {
        float e = emb[(size_t)n * 64 + lane] * rs[n];
        float a = 0.f;
        int ei = __float_as_int(e);
#pragma unroll
        for (int k = 0; k < 64; ++k) {
            a += __int_as_float(__builtin_amdgcn_readlane(ei, k)) * w1c[k];
        }
        h16[(size_t)n * 64 + lane] = (unsigned short)f32_to_bf16(a);
    }
}

// Pure gather + epilogue: wave per node, bf16 h, 8 gathers in flight.
__global__ void k_agg_post(const int* __restrict__ row_start,
                           const int* __restrict__ col,
                           const unsigned short* __restrict__ h16,
                           const float* __restrict__ W2,
                           const float* __restrict__ b2,
                           float* __restrict__ z) {
    int gtid = blockIdx.x * blockDim.x + threadIdx.x;
    int n    = gtid >> 6;
    int lane = threadIdx.x & 63;
    if (n >= N_NODES) return;
    int start = row_start[n];
    int end   = row_start[n + 1];
    float acc = 0.f;
    int i = start;
    for (; i + 7 < end; i += 8) {
        int s0 = col[i],     s1 = col[i + 1], s2 = col[i + 2], s3 = col[i + 3];
        int s4 = col[i + 4], s5 = col[i + 5], s6 = col[i + 6], s7 = col[i + 7];
        float v0 = bf16_to_f32(h16[(size_t)s0 * 64 + lane]);
        float v1 = bf16_to_f32(h16[(size_t)s1 * 64 + lane]);
        float v2 = bf16_to_f32(h16[(size_t)s2 * 64 + lane]);
        float v3 = bf16_to_f32(h16[(size_t)s3 * 64 + lane]);
        float v4 = bf16_to_f32(h16[(size_t)s4 * 64 + lane]);
        float v5 = bf16_to_f32(h16[(size_t)s5 * 64 + lane]);
        float v6 = bf16_to_f32(h16[(size_t)s6 * 64 + lane]);
        float v7 = bf16_to_f32(h16[(size_t)s7 * 64 + lane]);
        acc += ((v0 + v1) + (v2 + v3)) + ((v4 + v5) + (v6 + v7));
    }
    for (; i + 3 < end; i += 4) {
        int s0 = col[i], s1 = col[i + 1], s2 = col[i + 2], s3 = col[i + 3];
        float v0 = bf16_to_f32(h16[(size_t)s0 * 64 + lane]);
        float v1 = bf16_to_f32(h16[(size_t)s1 * 64 + lane]);
        float v2 = bf16_to_f32(h16[(size_t)s2 * 64 + lane]);
        float v3 = bf16_to_f32(h16[(size_t)s3 * 64 + lane]);
        acc += (v0 + v1) + (v2 + v3);
    }
    for (; i < end; ++i) acc += bf16_to_f32(h16[(size_t)col[i] * 64 + lane]);

    float x = acc * rsqrtf(fmaxf((float)(end - start), 1.0f));
    x = (x > 0.f) ? x : 0.01f * x;
    float p = x * W2[lane];
#pragma unroll
    for (int off = 32; off > 0; off >>= 1) p += __shfl_xor(p, off, 64);
    if (lane == 0) z[n] = p + b2[0];
}

// thread per node: out[n] = sigmoid( sum over in-edges z[s] )
__global__ void k_agg2_sigmoid(const int* __restrict__ row_start,
                               const int* __restrict__ col,
                               const float* __restrict__ z,
                               float* __restrict__ out) {
    int n = blockIdx.x * blockDim.x + threadIdx.x;
    if (n >= N_NODES) return;
    int start = row_start[n];
    int end   = row_start[n + 1];
    float acc = 0.f;
    int i = start;
    for (; i + 3 < end; i += 4) {
        float a = z[col[i]], b = z[col[i + 1]];
        float c = z[col[i + 2]], d = z[col[i + 3]];
        acc += (a + b) + (c + d);
    }
    for (; i < end; ++i) acc += z[col[i]];
    out[n] = 1.0f / (1.0f + expf(-acc));
}

extern "C" void kernel_launch(void* const* d_in, const int* in_sizes, int n_in,
                              void* d_out, int out_size, void* d_ws, size_t ws_size,
                              hipStream_t stream) {
    const int* node_ids   = (const int*)d_in[0];  (void)node_ids; // arange
    const int* senders    = (const int*)d_in[1];
    const int* receivers  = (const int*)d_in[2];
    const float* emb      = (const float*)d_in[3];
    const float* W1       = (const float*)d_in[4];
    const float* W2       = (const float*)d_in[5];
    const float* b2       = (const float*)d_in[6];
    float* out            = (float*)d_out;

    char* ws = (char*)d_ws;
    unsigned*       ghist_s   = (unsigned*)(ws);
    unsigned*       ghist_r   = (unsigned*)(ws + 6400000);
    int*            coff      = (int*)(ws + 12800000);
    int*            cnt_r     = (int*)(ws + 25600000);
    int*            row_start = (int*)(ws + 26000000);
    int*            blockSums = (int*)(ws + 26400016);
    int*            blockOffs = (int*)(ws + 26401600);
    float*          rs        = (float*)(ws + 26403200);
    int*            col       = (int*)(ws + 26803200);
    unsigned short* h16       = (unsigned short*)(ws + 30803200);
    float*          z         = (float*)(ws + 43603200);

    const int B = 256;
    k_hist<<<2 * RANGES * CHUNKS, 1024, 0, stream>>>(senders, receivers, ghist_s, ghist_r);
    k_scanA2<<<N_BLOCKS_SCAN, SCAN_B, 0, stream>>>(ghist_s, ghist_r, cnt_r, rs, blockSums);
    k_scanB<<<1, 512, 0, stream>>>(blockSums, blockOffs);
    k_scanCD<<<N_BLOCKS_SCAN, SCAN_B, 0, stream>>>(cnt_r, blockOffs, ghist_r, row_start, coff);
    k_fill2h<<<256, 1024, 0, stream>>>(senders, receivers, coff, col, emb, rs, W1, h16);
    k_agg_post<<<(N_NODES * 64 + B - 1) / B, B, 0, stream>>>(row_start, col, h16, W2, b2, z);
    k_agg2_sigmoid<<<(N_NODES + B - 1) / B, B, 0, stream>>>(row_start, col, z, out);
}